// Round 28
// baseline (133.688 us; speedup 1.0000x reference)
//
#include <hip/hip_runtime.h>
#include <math.h>

constexpr int NN   = 100000;   // nodes
constexpr int DIM  = 128;
constexpr int NE   = 3200000;  // edges
constexpr int NCLS = 40;
constexpr float EPSF = 1e-7f;

constexpr int BSH  = 9;                      // 512 cols per coarse bucket
constexpr int BSZ  = 1 << BSH;
constexpr int NBKT = (NN + BSZ - 1) >> BSH;  // 196
constexpr int CAP  = 18432;                  // bucket capacity
constexpr int AEPB = 4096;                   // edges per binA block (35KB LDS)
constexpr int ABLK = (NE + AEPB - 1) / AEPB; // 782

constexpr int GSTR = 64;                     // g row stride in halfwords (128 B)

typedef __attribute__((ext_vector_type(8))) short bf16x8;
typedef __attribute__((ext_vector_type(8))) unsigned short u16x8;
typedef __attribute__((ext_vector_type(4))) float f32x4;

__device__ __forceinline__ unsigned short f2bf(float f) {
    unsigned u = __builtin_bit_cast(unsigned, f);
    unsigned r = u + 0x7FFFu + ((u >> 16) & 1u);
    return (unsigned short)(r >> 16);
}
__device__ __forceinline__ float bf2f(unsigned short b) {
    return __builtin_bit_cast(float, (unsigned)b << 16);
}

// ---- hybrid: bid%4==0 -> binA bucket-partition block; else -> h MFMA block.
// 1:3 ratio matches the ~24% binA work share (was 1:2 in R27).
__global__ __launch_bounds__(256) void hybrid_kernel(
    const int* __restrict__ row, const int* __restrict__ col,
    int* __restrict__ gcur, unsigned* __restrict__ pairs,
    const float* __restrict__ xE, const float* __restrict__ xH,
    const float* __restrict__ xS, const unsigned short* __restrict__ wbf,
    unsigned short* __restrict__ gbf) {

    __shared__ int hist[256];
    __shared__ int lofx[256];
    __shared__ int gbase[256];
    __shared__ unsigned sortedw[AEPB];   // 16 KB
    __shared__ int dstg[AEPB];           // 16 KB

    int bid = blockIdx.x;
    int t = threadIdx.x;

    if ((bid & 3) == 0) {
        // ================= binA block =================
        int e0 = (bid >> 2) * AEPB;
        int cnt = min(AEPB, NE - e0);

        hist[t] = 0;
        __syncthreads();
        for (int k = t; k < cnt; k += 256) atomicAdd(&hist[col[e0 + k] >> BSH], 1);
        __syncthreads();

        int h = hist[t];
        if (t < NBKT && h > 0) gbase[t] = atomicAdd(&gcur[t], h);
        lofx[t] = h;
        __syncthreads();
        for (int d = 1; d < 256; d <<= 1) {
            int o = (t >= d) ? lofx[t - d] : 0;
            __syncthreads();
            lofx[t] += o;
            __syncthreads();
        }
        int excl = lofx[t] - h;
        lofx[t] = excl;
        hist[t] = excl;
        __syncthreads();

        for (int k = t; k < cnt; k += 256) {
            int c = col[e0 + k], r = row[e0 + k];
            int b = c >> BSH;
            int pos = atomicAdd(&hist[b], 1);
            sortedw[pos] = ((unsigned)(c & (BSZ - 1)) << 17) | (unsigned)r;
            dstg[pos] = b * CAP + gbase[b] + (pos - lofx[b]);
        }
        __syncthreads();
        for (int k = t; k < cnt; k += 256) pairs[dstg[k]] = sortedw[k];
        return;
    }

    // ================= h block (R25 body, no dinv fold) =================
    int hidx = 3 * (bid >> 2) + (bid & 3) - 1;
    int n0 = hidx * 64;
    if (n0 >= NN) return;

    int lane = t & 63;
    int wv = t >> 6;                 // wave id 0..3
    int r  = lane & 15;              // A row / C col
    int kq = lane >> 4;              // k-quarter
    int myrow = n0 + 16 * wv + r;
    bool rowok = myrow < NN;

    f32x4 acc0 = {0.f, 0.f, 0.f, 0.f};
    f32x4 acc1 = acc0, acc2 = acc0;

    const bf16x8* wfr = reinterpret_cast<const bf16x8*>(wbf);

    for (int m = 0; m < 3; ++m) {
        const float* xb = (m == 0) ? xE : (m == 1) ? xH : xS;
        const float* xrow = xb + (size_t)myrow * DIM;

        float4 xf[8];
#pragma unroll
        for (int kc4 = 0; kc4 < 4; ++kc4) {
            int off = kc4 * 32 + kq * 8;
            xf[2 * kc4]     = rowok ? *reinterpret_cast<const float4*>(xrow + off)
                                    : make_float4(0.f, 0.f, 0.f, 0.f);
            xf[2 * kc4 + 1] = rowok ? *reinterpret_cast<const float4*>(xrow + off + 4)
                                    : make_float4(0.f, 0.f, 0.f, 0.f);
        }

        float scm = 1.f;
        if (m > 0) {
            float x0 = rowok ? xrow[0] : 1.f;   // guard -> scm=0, no NaN
            if (m == 1) {
                scm = acoshf(fmaxf(x0, 1.f)) * rsqrtf(fmaxf(x0 * x0 - 1.f, EPSF));
            } else {
                float cc = fminf(fmaxf(x0, -1.f), 1.f);
                scm = acosf(cc) * rsqrtf(fmaxf(1.f - x0 * x0, EPSF));
            }
        }

#pragma unroll
        for (int kc4 = 0; kc4 < 4; ++kc4) {
            float4 f0 = xf[2 * kc4], f1 = xf[2 * kc4 + 1];
            float a[8] = {f0.x, f0.y, f0.z, f0.w, f1.x, f1.y, f1.z, f1.w};
            if (m > 0 && kc4 == 0 && kq == 0) a[0] = 0.f;   // logmap zeroes k=0

            bf16x8 ah;
#pragma unroll
            for (int j = 0; j < 8; ++j)
                ah[j] = (short)f2bf(a[j] * scm);

            int kc = m * 4 + kc4;
            const bf16x8* wb = wfr + (size_t)(kc * 3) * 2 * 64;
            bf16x8 bh0 = wb[0 * 128 + 0 * 64 + lane];
            bf16x8 bl0 = wb[0 * 128 + 1 * 64 + lane];
            bf16x8 bh1 = wb[1 * 128 + 0 * 64 + lane];
            bf16x8 bl1 = wb[1 * 128 + 1 * 64 + lane];
            bf16x8 bh2 = wb[2 * 128 + 0 * 64 + lane];
            bf16x8 bl2 = wb[2 * 128 + 1 * 64 + lane];

            acc0 = __builtin_amdgcn_mfma_f32_16x16x32_bf16(ah, bh0, acc0, 0, 0, 0);
            acc0 = __builtin_amdgcn_mfma_f32_16x16x32_bf16(ah, bl0, acc0, 0, 0, 0);
            acc1 = __builtin_amdgcn_mfma_f32_16x16x32_bf16(ah, bh1, acc1, 0, 0, 0);
            acc1 = __builtin_amdgcn_mfma_f32_16x16x32_bf16(ah, bl1, acc1, 0, 0, 0);
            acc2 = __builtin_amdgcn_mfma_f32_16x16x32_bf16(ah, bh2, acc2, 0, 0, 0);
            acc2 = __builtin_amdgcn_mfma_f32_16x16x32_bf16(ah, bl2, acc2, 0, 0, 0);
        }
    }

    // C/D: node = nbase + i ; class = 16t + r   [m89 layout]; g = h (no dinv)
    int nbase = n0 + 16 * wv + 4 * kq;
#pragma unroll
    for (int i = 0; i < 4; ++i) {
        int n = nbase + i;
        if (n < NN) {
            unsigned short* gr = gbf + (size_t)n * GSTR;
            gr[r]      = f2bf(acc0[i]);
            gr[16 + r] = f2bf(acc1[i]);
            if (r < 8)
                gr[32 + r] = f2bf(acc2[i]);
        }
    }
}

// ---- dinv + scale: per-bucket histogram, then fold dinv into g rows --------
__global__ __launch_bounds__(1024) void dinvscale_kernel(
    const int* __restrict__ gcur, const unsigned* __restrict__ pairs,
    unsigned short* __restrict__ gbf) {
    __shared__ int hist[BSZ];
    int t = threadIdx.x;
    int b = blockIdx.x;
    if (t < BSZ) hist[t] = 0;
    __syncthreads();
    int cnt = gcur[b];
    const unsigned* pb = pairs + (size_t)b * CAP;
    for (int i = t; i < cnt; i += 1024) atomicAdd(&hist[pb[i] >> 17], 1);
    __syncthreads();

    // scale rows [b*512, +512): g *= rsqrt(deg+1)
    for (int task = t; task < BSZ * 5; task += 1024) {
        int c = task / 5;
        int q = task - c * 5;
        int n = (b << BSH) + c;
        if (n >= NN) continue;
        float di = rsqrtf((float)(hist[c] + 1));   // +1 self loop
        u16x8* gp = reinterpret_cast<u16x8*>(gbf + (size_t)n * GSTR) + q;
        u16x8 v = *gp;
#pragma unroll
        for (int k = 0; k < 8; ++k) v[k] = (short)f2bf(bf2f(v[k]) * di);
        *gp = v;
    }
}

// ---- wpack: W[384][40] f32 -> hi/lo bf16 B-fragments in MFMA lane order ----
__global__ __launch_bounds__(256) void wpack_kernel(const float* __restrict__ W,
                                                    unsigned short* __restrict__ wbf) {
    int idx = blockIdx.x * 256 + threadIdx.x;
    if (idx >= 12 * 3 * 2 * 64 * 8) return;
    int j    = idx & 7;
    int lane = (idx >> 3) & 63;
    int hl   = (idx >> 9) & 1;
    int rest = idx >> 10;          // kc*3 + t
    int t    = rest % 3;
    int kc   = rest / 3;
    int k = kc * 32 + 8 * (lane >> 4) + j;
    int c = 16 * t + (lane & 15);
    float w = (c < NCLS) ? W[k * NCLS + c] : 0.f;
    unsigned short hi = f2bf(w);
    wbf[idx] = (hl == 0) ? hi : f2bf(w - bf2f(hi));
}

// ---- fused binB+gather: sort bucket in LDS, gather straight from LDS -------
__global__ __launch_bounds__(1024) void fusedBG_kernel(
    const int* __restrict__ gcur, const unsigned* __restrict__ pairs,
    const unsigned short* __restrict__ gbf, float* __restrict__ out) {

    __shared__ int srow[CAP];      // 73,728 B
    __shared__ int hist[512];      //  2,048 B (count -> cursor)
    __shared__ int sc[1024];       //  4,096 B (scan temp; [0,512) = col starts)

    int t = threadIdx.x;
    int b = blockIdx.x;
    int cnt = gcur[b];
    const unsigned* pb = pairs + (size_t)b * CAP;

    if (t < 512) hist[t] = 0;
    __syncthreads();
    for (int i = t; i < cnt; i += 1024) atomicAdd(&hist[pb[i] >> 17], 1);
    __syncthreads();

    int v = (t < 512) ? hist[t] : 0;
    sc[t] = v;
    __syncthreads();
    for (int d = 1; d < 1024; d <<= 1) {
        int o = (t >= d) ? sc[t - d] : 0;
        __syncthreads();
        sc[t] += o;
        __syncthreads();
    }
    int excl = sc[t] - v;
    __syncthreads();
    if (t < 512) { sc[t] = excl; hist[t] = excl; }   // sc = start, hist = cursor
    __syncthreads();

    for (int i = t; i < cnt; i += 1024) {
        unsigned w = pb[i];                           // L2-warm re-read
        int pos = atomicAdd(&hist[w >> 17], 1);
        srow[pos] = (int)(w & 0x1FFFFu);
    }
    __syncthreads();

    // gather: task = (col c, class-octet c8); edges from LDS srow[sc[c]..)
    const u16x8* gball = reinterpret_cast<const u16x8*>(gbf);
    for (int task = t; task < BSZ * 5; task += 1024) {
        int c  = task / 5;
        int c8 = task - c * 5;
        int n = (b << BSH) + c;
        if (n >= NN) continue;
        int s = sc[c];
        int e = (c == BSZ - 1) ? cnt : sc[c + 1];
        float dinv = rsqrtf((float)(e - s + 1));

        const u16x8* gb = gball + c8;
        u16x8 sv = gb[(size_t)n * 8];     // self loop (dinv[n] folded in g)
        float a0[8], a1[8], a2[8], a3[8];
#pragma unroll
        for (int k = 0; k < 8; ++k) {
            a0[k] = bf2f(sv[k]); a1[k] = 0.f; a2[k] = 0.f; a3[k] = 0.f;
        }

        int j = s;
        for (; j + 3 < e; j += 4) {
            int r0 = srow[j], r1 = srow[j + 1], r2 = srow[j + 2], r3 = srow[j + 3];
            u16x8 v0 = gb[(size_t)r0 * 8];
            u16x8 v1 = gb[(size_t)r1 * 8];
            u16x8 v2 = gb[(size_t)r2 * 8];
            u16x8 v3 = gb[(size_t)r3 * 8];
#pragma unroll
            for (int k = 0; k < 8; ++k) {
                a0[k] += bf2f(v0[k]); a1[k] += bf2f(v1[k]);
                a2[k] += bf2f(v2[k]); a3[k] += bf2f(v3[k]);
            }
        }
        for (; j < e; ++j) {
            u16x8 vv = gb[(size_t)srow[j] * 8];
#pragma unroll
            for (int k = 0; k < 8; ++k) a0[k] += bf2f(vv[k]);
        }

        float* on = out + (size_t)n * NCLS + c8 * 8;
        float4 o0, o1;
        o0.x = (a0[0] + a1[0] + a2[0] + a3[0]) * dinv;
        o0.y = (a0[1] + a1[1] + a2[1] + a3[1]) * dinv;
        o0.z = (a0[2] + a1[2] + a2[2] + a3[2]) * dinv;
        o0.w = (a0[3] + a1[3] + a2[3] + a3[3]) * dinv;
        o1.x = (a0[4] + a1[4] + a2[4] + a3[4]) * dinv;
        o1.y = (a0[5] + a1[5] + a2[5] + a3[5]) * dinv;
        o1.z = (a0[6] + a1[6] + a2[6] + a3[6]) * dinv;
        o1.w = (a0[7] + a1[7] + a2[7] + a3[7]) * dinv;
        *reinterpret_cast<float4*>(on)     = o0;
        *reinterpret_cast<float4*>(on + 4) = o1;
    }
}

extern "C" void kernel_launch(void* const* d_in, const int* in_sizes, int n_in,
                              void* d_out, int out_size, void* d_ws, size_t ws_size,
                              hipStream_t stream) {
    const float* xE = (const float*)d_in[0];
    const float* xH = (const float*)d_in[1];
    const float* xS = (const float*)d_in[2];
    const float* W  = (const float*)d_in[3];
    const int*   ei = (const int*)d_in[4];
    const int* row = ei;            // edge_index[0]
    const int* col = ei + NE;       // edge_index[1]
    float* out = (float*)d_out;

    auto pad = [](size_t x) { return (x + 255) & ~(size_t)255; };
    char* p = (char*)d_ws;
    int* gcur = (int*)p;                p += pad((size_t)NBKT * 4);
    unsigned* pairs = (unsigned*)p;     p += pad((size_t)NBKT * CAP * 4);   // 14.45 MB
    unsigned short* gbf = (unsigned short*)p;
    p += pad((size_t)NN * GSTR * 2);    // 12.8 MB
    unsigned short* wbf = (unsigned short*)p;                               // 147 KB

    hipMemsetAsync(gcur, 0, (size_t)NBKT * 4, stream);

    wpack_kernel<<<(12 * 3 * 2 * 64 * 8 + 255) / 256, 256, 0, stream>>>(W, wbf);
    hybrid_kernel<<<ABLK * 4, 256, 0, stream>>>(row, col, gcur, pairs,
                                                xE, xH, xS, wbf, gbf);
    dinvscale_kernel<<<NBKT, 1024, 0, stream>>>(gcur, pairs, gbf);
    fusedBG_kernel<<<NBKT, 1024, 0, stream>>>(gcur, pairs, gbf, out);
}

// Round 29
// 130.241 us; speedup vs baseline: 1.0265x; 1.0265x over previous
//
#include <hip/hip_runtime.h>
#include <math.h>

constexpr int NN   = 100000;   // nodes
constexpr int DIM  = 128;
constexpr int NE   = 3200000;  // edges
constexpr int NCLS = 40;
constexpr float EPSF = 1e-7f;

constexpr int BSH  = 9;                      // 512 cols per coarse bucket
constexpr int BSZ  = 1 << BSH;
constexpr int NBKT = (NN + BSZ - 1) >> BSH;  // 196
constexpr int CAP  = 18432;                  // bucket capacity
constexpr int AEPB = 4096;                   // edges per binA block
constexpr int ABLK = (NE + AEPB - 1) / AEPB; // 782

constexpr int GSTR = 64;                     // g row stride in halfwords (128 B)

typedef __attribute__((ext_vector_type(8))) short bf16x8;
typedef __attribute__((ext_vector_type(8))) unsigned short u16x8;
typedef __attribute__((ext_vector_type(4))) float f32x4;

__device__ __forceinline__ unsigned short f2bf(float f) {
    unsigned u = __builtin_bit_cast(unsigned, f);
    unsigned r = u + 0x7FFFu + ((u >> 16) & 1u);
    return (unsigned short)(r >> 16);
}
__device__ __forceinline__ float bf2f(unsigned short b) {
    return __builtin_bit_cast(float, (unsigned)b << 16);
}

// ---- hybrid: bid%3==0 -> binA bucket-partition block; else -> h MFMA block.
__global__ __launch_bounds__(256) void hybrid_kernel(
    const int* __restrict__ row, const int* __restrict__ col,
    int* __restrict__ gcur, unsigned* __restrict__ pairs,
    const float* __restrict__ xE, const float* __restrict__ xH,
    const float* __restrict__ xS, const unsigned short* __restrict__ wbf,
    unsigned short* __restrict__ gbf) {

    __shared__ int hist[256];
    __shared__ int lofx[256];
    __shared__ int gbase[256];
    __shared__ unsigned sortedw[AEPB];   // 16 KB
    __shared__ int dstg[AEPB];           // 16 KB

    int bid = blockIdx.x;
    int t = threadIdx.x;

    if (bid % 3 == 0) {
        // ================= binA block =================
        int e0 = (bid / 3) * AEPB;
        int cnt = min(AEPB, NE - e0);

        hist[t] = 0;
        __syncthreads();
        for (int k = t; k < cnt; k += 256) atomicAdd(&hist[col[e0 + k] >> BSH], 1);
        __syncthreads();

        int h = hist[t];
        if (t < NBKT && h > 0) gbase[t] = atomicAdd(&gcur[t], h);
        lofx[t] = h;
        __syncthreads();
        for (int d = 1; d < 256; d <<= 1) {
            int o = (t >= d) ? lofx[t - d] : 0;
            __syncthreads();
            lofx[t] += o;
            __syncthreads();
        }
        int excl = lofx[t] - h;
        lofx[t] = excl;
        hist[t] = excl;
        __syncthreads();

        for (int k = t; k < cnt; k += 256) {
            int c = col[e0 + k], r = row[e0 + k];
            int b = c >> BSH;
            int pos = atomicAdd(&hist[b], 1);
            sortedw[pos] = ((unsigned)(c & (BSZ - 1)) << 17) | (unsigned)r;
            dstg[pos] = b * CAP + gbase[b] + (pos - lofx[b]);
        }
        __syncthreads();
        for (int k = t; k < cnt; k += 256) pairs[dstg[k]] = sortedw[k];
        return;
    }

    // ================= h block (R25 body, no dinv fold) =================
    int hidx = 2 * (bid / 3) + (bid % 3) - 1;
    int n0 = hidx * 64;
    if (n0 >= NN) return;

    int lane = t & 63;
    int wv = t >> 6;                 // wave id 0..3
    int r  = lane & 15;              // A row / C col
    int kq = lane >> 4;              // k-quarter
    int myrow = n0 + 16 * wv + r;
    bool rowok = myrow < NN;

    f32x4 acc0 = {0.f, 0.f, 0.f, 0.f};
    f32x4 acc1 = acc0, acc2 = acc0;

    const bf16x8* wfr = reinterpret_cast<const bf16x8*>(wbf);

    for (int m = 0; m < 3; ++m) {
        const float* xb = (m == 0) ? xE : (m == 1) ? xH : xS;
        const float* xrow = xb + (size_t)myrow * DIM;

        float4 xf[8];
#pragma unroll
        for (int kc4 = 0; kc4 < 4; ++kc4) {
            int off = kc4 * 32 + kq * 8;
            xf[2 * kc4]     = rowok ? *reinterpret_cast<const float4*>(xrow + off)
                                    : make_float4(0.f, 0.f, 0.f, 0.f);
            xf[2 * kc4 + 1] = rowok ? *reinterpret_cast<const float4*>(xrow + off + 4)
                                    : make_float4(0.f, 0.f, 0.f, 0.f);
        }

        float scm = 1.f;
        if (m > 0) {
            float x0 = rowok ? xrow[0] : 1.f;   // guard -> scm=0, no NaN
            if (m == 1) {
                scm = acoshf(fmaxf(x0, 1.f)) * rsqrtf(fmaxf(x0 * x0 - 1.f, EPSF));
            } else {
                float cc = fminf(fmaxf(x0, -1.f), 1.f);
                scm = acosf(cc) * rsqrtf(fmaxf(1.f - x0 * x0, EPSF));
            }
        }

#pragma unroll
        for (int kc4 = 0; kc4 < 4; ++kc4) {
            float4 f0 = xf[2 * kc4], f1 = xf[2 * kc4 + 1];
            float a[8] = {f0.x, f0.y, f0.z, f0.w, f1.x, f1.y, f1.z, f1.w};
            if (m > 0 && kc4 == 0 && kq == 0) a[0] = 0.f;   // logmap zeroes k=0

            bf16x8 ah;
#pragma unroll
            for (int j = 0; j < 8; ++j)
                ah[j] = (short)f2bf(a[j] * scm);

            int kc = m * 4 + kc4;
            const bf16x8* wb = wfr + (size_t)(kc * 3) * 2 * 64;
            bf16x8 bh0 = wb[0 * 128 + 0 * 64 + lane];
            bf16x8 bl0 = wb[0 * 128 + 1 * 64 + lane];
            bf16x8 bh1 = wb[1 * 128 + 0 * 64 + lane];
            bf16x8 bl1 = wb[1 * 128 + 1 * 64 + lane];
            bf16x8 bh2 = wb[2 * 128 + 0 * 64 + lane];
            bf16x8 bl2 = wb[2 * 128 + 1 * 64 + lane];

            acc0 = __builtin_amdgcn_mfma_f32_16x16x32_bf16(ah, bh0, acc0, 0, 0, 0);
            acc0 = __builtin_amdgcn_mfma_f32_16x16x32_bf16(ah, bl0, acc0, 0, 0, 0);
            acc1 = __builtin_amdgcn_mfma_f32_16x16x32_bf16(ah, bh1, acc1, 0, 0, 0);
            acc1 = __builtin_amdgcn_mfma_f32_16x16x32_bf16(ah, bl1, acc1, 0, 0, 0);
            acc2 = __builtin_amdgcn_mfma_f32_16x16x32_bf16(ah, bh2, acc2, 0, 0, 0);
            acc2 = __builtin_amdgcn_mfma_f32_16x16x32_bf16(ah, bl2, acc2, 0, 0, 0);
        }
    }

    // C/D: node = nbase + i ; class = 16t + r   [m89 layout]; g = h (no dinv)
    int nbase = n0 + 16 * wv + 4 * kq;
#pragma unroll
    for (int i = 0; i < 4; ++i) {
        int n = nbase + i;
        if (n < NN) {
            unsigned short* gr = gbf + (size_t)n * GSTR;
            gr[r]      = f2bf(acc0[i]);
            gr[16 + r] = f2bf(acc1[i]);
            if (r < 8)
                gr[32 + r] = f2bf(acc2[i]);
        }
    }
}

// ---- dinv + scale: per-bucket histogram, then fold dinv into g rows --------
__global__ __launch_bounds__(1024) void dinvscale_kernel(
    const int* __restrict__ gcur, const unsigned* __restrict__ pairs,
    unsigned short* __restrict__ gbf) {
    __shared__ int hist[BSZ];
    int t = threadIdx.x;
    int b = blockIdx.x;
    if (t < BSZ) hist[t] = 0;
    __syncthreads();
    int cnt = gcur[b];
    const unsigned* pb = pairs + (size_t)b * CAP;
    for (int i = t; i < cnt; i += 1024) atomicAdd(&hist[pb[i] >> 17], 1);
    __syncthreads();

    // scale rows [b*512, +512): g *= rsqrt(deg+1)
    for (int task = t; task < BSZ * 5; task += 1024) {
        int c = task / 5;
        int q = task - c * 5;
        int n = (b << BSH) + c;
        if (n >= NN) continue;
        float di = rsqrtf((float)(hist[c] + 1));   // +1 self loop
        u16x8* gp = reinterpret_cast<u16x8*>(gbf + (size_t)n * GSTR) + q;
        u16x8 v = *gp;
#pragma unroll
        for (int k = 0; k < 8; ++k) v[k] = (short)f2bf(bf2f(v[k]) * di);
        *gp = v;
    }
}

// ---- wpack: W[384][40] f32 -> hi/lo bf16 B-fragments in MFMA lane order ----
__global__ __launch_bounds__(256) void wpack_kernel(const float* __restrict__ W,
                                                    unsigned short* __restrict__ wbf) {
    int idx = blockIdx.x * 256 + threadIdx.x;
    if (idx >= 12 * 3 * 2 * 64 * 8) return;
    int j    = idx & 7;
    int lane = (idx >> 3) & 63;
    int hl   = (idx >> 9) & 1;
    int rest = idx >> 10;          // kc*3 + t
    int t    = rest % 3;
    int kc   = rest / 3;
    int k = kc * 32 + 8 * (lane >> 4) + j;
    int c = 16 * t + (lane & 15);
    float w = (c < NCLS) ? W[k * NCLS + c] : 0.f;
    unsigned short hi = f2bf(w);
    wbf[idx] = (hl == 0) ? hi : f2bf(w - bf2f(hi));
}

// ---- fused binB+gather: sort bucket in LDS, gather straight from LDS -------
// Gather loop: 8 loads in flight per iteration, 4 accumulator chains.
__global__ __launch_bounds__(1024) void fusedBG_kernel(
    const int* __restrict__ gcur, const unsigned* __restrict__ pairs,
    const unsigned short* __restrict__ gbf, float* __restrict__ out) {

    __shared__ int srow[CAP];      // 73,728 B
    __shared__ int hist[512];      //  2,048 B (count -> cursor)
    __shared__ int sc[1024];       //  4,096 B (scan temp; [0,512) = col starts)

    int t = threadIdx.x;
    int b = blockIdx.x;
    int cnt = gcur[b];
    const unsigned* pb = pairs + (size_t)b * CAP;

    if (t < 512) hist[t] = 0;
    __syncthreads();
    for (int i = t; i < cnt; i += 1024) atomicAdd(&hist[pb[i] >> 17], 1);
    __syncthreads();

    int v = (t < 512) ? hist[t] : 0;
    sc[t] = v;
    __syncthreads();
    for (int d = 1; d < 1024; d <<= 1) {
        int o = (t >= d) ? sc[t - d] : 0;
        __syncthreads();
        sc[t] += o;
        __syncthreads();
    }
    int excl = sc[t] - v;
    __syncthreads();
    if (t < 512) { sc[t] = excl; hist[t] = excl; }   // sc = start, hist = cursor
    __syncthreads();

    for (int i = t; i < cnt; i += 1024) {
        unsigned w = pb[i];                           // L2-warm re-read
        int pos = atomicAdd(&hist[w >> 17], 1);
        srow[pos] = (int)(w & 0x1FFFFu);
    }
    __syncthreads();

    // gather: task = (col c, class-octet c8); edges from LDS srow[sc[c]..)
    const u16x8* gball = reinterpret_cast<const u16x8*>(gbf);
    for (int task = t; task < BSZ * 5; task += 1024) {
        int c  = task / 5;
        int c8 = task - c * 5;
        int n = (b << BSH) + c;
        if (n >= NN) continue;
        int s = sc[c];
        int e = (c == BSZ - 1) ? cnt : sc[c + 1];
        float dinv = rsqrtf((float)(e - s + 1));

        const u16x8* gb = gball + c8;
        u16x8 sv = gb[(size_t)n * 8];     // self loop (dinv[n] folded in g)
        float a0[8], a1[8], a2[8], a3[8];
#pragma unroll
        for (int k = 0; k < 8; ++k) {
            a0[k] = bf2f(sv[k]); a1[k] = 0.f; a2[k] = 0.f; a3[k] = 0.f;
        }

        int j = s;
        for (; j + 7 < e; j += 8) {
            int r0 = srow[j],     r1 = srow[j + 1], r2 = srow[j + 2], r3 = srow[j + 3];
            int r4 = srow[j + 4], r5 = srow[j + 5], r6 = srow[j + 6], r7 = srow[j + 7];
            u16x8 v0 = gb[(size_t)r0 * 8];
            u16x8 v1 = gb[(size_t)r1 * 8];
            u16x8 v2 = gb[(size_t)r2 * 8];
            u16x8 v3 = gb[(size_t)r3 * 8];
            u16x8 v4 = gb[(size_t)r4 * 8];
            u16x8 v5 = gb[(size_t)r5 * 8];
            u16x8 v6 = gb[(size_t)r6 * 8];
            u16x8 v7 = gb[(size_t)r7 * 8];
#pragma unroll
            for (int k = 0; k < 8; ++k) {
                a0[k] += bf2f(v0[k]) + bf2f(v4[k]);
                a1[k] += bf2f(v1[k]) + bf2f(v5[k]);
                a2[k] += bf2f(v2[k]) + bf2f(v6[k]);
                a3[k] += bf2f(v3[k]) + bf2f(v7[k]);
            }
        }
        for (; j + 3 < e; j += 4) {
            int r0 = srow[j], r1 = srow[j + 1], r2 = srow[j + 2], r3 = srow[j + 3];
            u16x8 v0 = gb[(size_t)r0 * 8];
            u16x8 v1 = gb[(size_t)r1 * 8];
            u16x8 v2 = gb[(size_t)r2 * 8];
            u16x8 v3 = gb[(size_t)r3 * 8];
#pragma unroll
            for (int k = 0; k < 8; ++k) {
                a0[k] += bf2f(v0[k]); a1[k] += bf2f(v1[k]);
                a2[k] += bf2f(v2[k]); a3[k] += bf2f(v3[k]);
            }
        }
        for (; j < e; ++j) {
            u16x8 vv = gb[(size_t)srow[j] * 8];
#pragma unroll
            for (int k = 0; k < 8; ++k) a0[k] += bf2f(vv[k]);
        }

        float* on = out + (size_t)n * NCLS + c8 * 8;
        float4 o0, o1;
        o0.x = (a0[0] + a1[0] + a2[0] + a3[0]) * dinv;
        o0.y = (a0[1] + a1[1] + a2[1] + a3[1]) * dinv;
        o0.z = (a0[2] + a1[2] + a2[2] + a3[2]) * dinv;
        o0.w = (a0[3] + a1[3] + a2[3] + a3[3]) * dinv;
        o1.x = (a0[4] + a1[4] + a2[4] + a3[4]) * dinv;
        o1.y = (a0[5] + a1[5] + a2[5] + a3[5]) * dinv;
        o1.z = (a0[6] + a1[6] + a2[6] + a3[6]) * dinv;
        o1.w = (a0[7] + a1[7] + a2[7] + a3[7]) * dinv;
        *reinterpret_cast<float4*>(on)     = o0;
        *reinterpret_cast<float4*>(on + 4) = o1;
    }
}

extern "C" void kernel_launch(void* const* d_in, const int* in_sizes, int n_in,
                              void* d_out, int out_size, void* d_ws, size_t ws_size,
                              hipStream_t stream) {
    const float* xE = (const float*)d_in[0];
    const float* xH = (const float*)d_in[1];
    const float* xS = (const float*)d_in[2];
    const float* W  = (const float*)d_in[3];
    const int*   ei = (const int*)d_in[4];
    const int* row = ei;            // edge_index[0]
    const int* col = ei + NE;       // edge_index[1]
    float* out = (float*)d_out;

    auto pad = [](size_t x) { return (x + 255) & ~(size_t)255; };
    char* p = (char*)d_ws;
    int* gcur = (int*)p;                p += pad((size_t)NBKT * 4);
    unsigned* pairs = (unsigned*)p;     p += pad((size_t)NBKT * CAP * 4);   // 14.45 MB
    unsigned short* gbf = (unsigned short*)p;
    p += pad((size_t)NN * GSTR * 2);    // 12.8 MB
    unsigned short* wbf = (unsigned short*)p;                               // 147 KB

    hipMemsetAsync(gcur, 0, (size_t)NBKT * 4, stream);

    wpack_kernel<<<(12 * 3 * 2 * 64 * 8 + 255) / 256, 256, 0, stream>>>(W, wbf);
    hybrid_kernel<<<ABLK * 3, 256, 0, stream>>>(row, col, gcur, pairs,
                                                xE, xH, xS, wbf, gbf);
    dinvscale_kernel<<<NBKT, 1024, 0, stream>>>(gcur, pairs, gbf);
    fusedBG_kernel<<<NBKT, 1024, 0, stream>>>(gcur, pairs, gbf, out);
}